// Round 1
// baseline (472.873 us; speedup 1.0000x reference)
//
#include <hip/hip_runtime.h>

// Problem constants
#define DD    256        // descriptor dim
#define KK    64         // clusters
#define NPIX  262144     // H*W
#define NT    64         // tile columns
#define GRID  256        // blocks (1 per CU)
#define TPB   16         // tiles per block (GRID*TPB*NT == NPIX)
#define BLOCK 512        // 8 waves

// LDS strides (elements)
#define XDN_S 72         // Xdn: [256][72] bf16, 16B-aligned rows, conflict-free b128
#define XND_S 258        // Xnd: [64][258] bf16, odd-dword stride -> scatter-write ~2-way
#define W_S   264        // W:   [64][264] bf16
#define AB_S  72         // Abar:[64][72]  bf16
#define SV_S  257        // V stage: [64][257] f32

typedef __attribute__((ext_vector_type(8))) short bf16x8;
typedef __attribute__((ext_vector_type(4))) float f32x4;

union Frag { bf16x8 v; int i[4]; };

__device__ __forceinline__ unsigned short f2bf(float f) {
    union { float f; unsigned u; } c; c.f = f;
    unsigned u = c.u;
    u += 0x7fffu + ((u >> 16) & 1u);       // round-to-nearest-even
    return (unsigned short)(u >> 16);
}
__device__ __forceinline__ int pack2(float a, float b) {
    return (int)((unsigned)f2bf(a) | ((unsigned)f2bf(b) << 16));
}

__global__ __launch_bounds__(BLOCK, 2)
void netvlad_fused(const float* __restrict__ x, const float* __restrict__ conv_w,
                   const float* __restrict__ conv_b, float* __restrict__ Vws,
                   float* __restrict__ asum_ws)
{
    __shared__ union {
        struct { short xdn[DD * XDN_S]; short xnd[NT * XND_S]; } a;  // 69888 B
        float sv[KK * SV_S];                                         // 65792 B
    } smA;
    __shared__ short Wl[KK * W_S];     // 33792 B
    __shared__ short Ab[KK * AB_S];    //  9216 B

    const int t    = threadIdx.x;
    const int lane = t & 63;
    const int w    = t >> 6;        // wave 0..7
    const int l15  = lane & 15;
    const int q    = (lane >> 4) & 3;

    // ---- stage W (fp32 -> bf16) into LDS, once ----
    #pragma unroll
    for (int i = 0; i < 32; ++i) {
        int idx = t + BLOCK * i;                 // 0..16383
        int k = idx >> 8, d = idx & 255;
        Wl[k * W_S + d] = (short)f2bf(conv_w[idx]);
    }

    // bias registers for logits waves: k = 16*mt + 4*q + r
    float breg[4][4];
    if (w < 4) {
        #pragma unroll
        for (int mt = 0; mt < 4; ++mt)
            #pragma unroll
            for (int r = 0; r < 4; ++r)
                breg[mt][r] = conv_b[16 * mt + 4 * q + r];
    }

    // V accumulators: wave owns d rows [32w, 32w+32), all 64 k cols
    f32x4 acc[2][4];
    #pragma unroll
    for (int mi = 0; mi < 2; ++mi)
        #pragma unroll
        for (int ct = 0; ct < 4; ++ct)
            acc[mi][ct] = (f32x4){0.f, 0.f, 0.f, 0.f};

    float asum[4][4];
    #pragma unroll
    for (int mt = 0; mt < 4; ++mt)
        #pragma unroll
        for (int r = 0; r < 4; ++r) asum[mt][r] = 0.f;

    __syncthreads();

    // staging mapping: thread covers rows d = j*32 + (t>>4), cols (t&15)*4 .. +3
    const int rowoff = t >> 4;           // 0..31
    const int coloff = (t & 15) * 4;     // 0..60

    // ---- prologue: prefetch tile 0 into registers ----
    float4 pre[8];
    {
        size_t n0 = (size_t)blockIdx.x * NT;
        #pragma unroll
        for (int j = 0; j < 8; ++j) {
            int d = j * 32 + rowoff;
            pre[j] = *(const float4*)(x + (size_t)d * NPIX + n0 + coloff);
        }
    }

    for (int it = 0; it < TPB; ++it) {
        __syncthreads();   // previous tile's LDS reads complete

        // ---- stage registers -> LDS (both layouts, bf16) ----
        #pragma unroll
        for (int j = 0; j < 8; ++j) {
            int d = j * 32 + rowoff;
            float4 v = pre[j];
            int2 pk; pk.x = pack2(v.x, v.y); pk.y = pack2(v.z, v.w);
            *(int2*)&smA.a.xdn[d * XDN_S + coloff] = pk;
            smA.a.xnd[(coloff + 0) * XND_S + d] = (short)f2bf(v.x);
            smA.a.xnd[(coloff + 1) * XND_S + d] = (short)f2bf(v.y);
            smA.a.xnd[(coloff + 2) * XND_S + d] = (short)f2bf(v.z);
            smA.a.xnd[(coloff + 3) * XND_S + d] = (short)f2bf(v.w);
        }

        // ---- prefetch next tile (stays in flight across barriers) ----
        if (it + 1 < TPB) {
            size_t n0 = ((size_t)blockIdx.x + (size_t)(it + 1) * GRID) * NT;
            #pragma unroll
            for (int j = 0; j < 8; ++j) {
                int d = j * 32 + rowoff;
                pre[j] = *(const float4*)(x + (size_t)d * NPIX + n0 + coloff);
            }
        }

        __syncthreads();   // staged tile visible

        // ---- logits + softmax (waves 0-3; wave owns n-tile w = 16 columns) ----
        if (w < 4) {
            f32x4 Lc[4];
            #pragma unroll
            for (int mt = 0; mt < 4; ++mt) Lc[mt] = (f32x4){0.f, 0.f, 0.f, 0.f};
            const int nloc = 16 * w + l15;
            #pragma unroll
            for (int ks = 0; ks < 8; ++ks) {
                Frag B;
                int base = nloc * XND_S + 32 * ks + 8 * q;
                B.i[0] = *(const int*)&smA.a.xnd[base + 0];
                B.i[1] = *(const int*)&smA.a.xnd[base + 2];
                B.i[2] = *(const int*)&smA.a.xnd[base + 4];
                B.i[3] = *(const int*)&smA.a.xnd[base + 6];
                #pragma unroll
                for (int mt = 0; mt < 4; ++mt) {
                    Frag A = *(const Frag*)&Wl[(16 * mt + l15) * W_S + 32 * ks + 8 * q];
                    Lc[mt] = __builtin_amdgcn_mfma_f32_16x16x32_bf16(A.v, B.v, Lc[mt], 0, 0, 0);
                }
            }
            // bias + max
            float mx = -1e30f;
            #pragma unroll
            for (int mt = 0; mt < 4; ++mt)
                #pragma unroll
                for (int r = 0; r < 4; ++r) {
                    Lc[mt][r] += breg[mt][r];
                    mx = fmaxf(mx, Lc[mt][r]);
                }
            mx = fmaxf(mx, __shfl_xor(mx, 16));
            mx = fmaxf(mx, __shfl_xor(mx, 32));
            float s = 0.f;
            float ev[4][4];
            #pragma unroll
            for (int mt = 0; mt < 4; ++mt)
                #pragma unroll
                for (int r = 0; r < 4; ++r) {
                    ev[mt][r] = __expf(Lc[mt][r] - mx);
                    s += ev[mt][r];
                }
            s += __shfl_xor(s, 16);
            s += __shfl_xor(s, 32);
            float inv = 1.0f / s;
            #pragma unroll
            for (int mt = 0; mt < 4; ++mt)
                #pragma unroll
                for (int r = 0; r < 4; ++r) {
                    float a = ev[mt][r] * inv;
                    asum[mt][r] += a;
                    Ab[(16 * mt + 4 * q + r) * AB_S + nloc] = (short)f2bf(a);
                }
        }

        __syncthreads();   // Abar visible

        // ---- VLAD GEMM: S^T tile, all 8 waves ----
        #pragma unroll
        for (int ks = 0; ks < 2; ++ks) {
            Frag Bf[4];
            #pragma unroll
            for (int ct = 0; ct < 4; ++ct)
                Bf[ct] = *(const Frag*)&Ab[(16 * ct + l15) * AB_S + 32 * ks + 8 * q];
            #pragma unroll
            for (int mi = 0; mi < 2; ++mi) {
                Frag Af = *(const Frag*)&smA.a.xdn[(32 * w + 16 * mi + l15) * XDN_S + 32 * ks + 8 * q];
                #pragma unroll
                for (int ct = 0; ct < 4; ++ct)
                    acc[mi][ct] = __builtin_amdgcn_mfma_f32_16x16x32_bf16(Af.v, Bf[ct].v, acc[mi][ct], 0, 0, 0);
            }
        }
    }

    // ---- epilogue: V partial -> LDS -> coalesced atomics ----
    __syncthreads();   // all V-GEMM LDS reads done before reuse
    #pragma unroll
    for (int mi = 0; mi < 2; ++mi)
        #pragma unroll
        for (int ct = 0; ct < 4; ++ct)
            #pragma unroll
            for (int r = 0; r < 4; ++r) {
                int k = 16 * ct + l15;
                int d = 32 * w + 16 * mi + 4 * q + r;
                smA.sv[k * SV_S + d] = acc[mi][ct][r];
            }
    __syncthreads();
    #pragma unroll
    for (int i = 0; i < 32; ++i) {
        int idx = t + BLOCK * i;
        int k = idx >> 8, d = idx & 255;
        atomicAdd(&Vws[idx], smA.sv[k * SV_S + d]);
    }
    if (w < 4) {
        #pragma unroll
        for (int mt = 0; mt < 4; ++mt)
            #pragma unroll
            for (int r = 0; r < 4; ++r) {
                float v = asum[mt][r];
                v += __shfl_xor(v, 1);
                v += __shfl_xor(v, 2);
                v += __shfl_xor(v, 4);
                v += __shfl_xor(v, 8);
                if (l15 == 0) atomicAdd(&asum_ws[16 * mt + 4 * q + r], v);
            }
    }
}

__global__ __launch_bounds__(1024)
void netvlad_finalize(const float* __restrict__ Vws, const float* __restrict__ asum_ws,
                      const float* __restrict__ c, float* __restrict__ y)
{
    __shared__ float sV[KK * DD];
    __shared__ float sa[KK];
    __shared__ float colf[DD];
    __shared__ float rowf[KK];
    const int t = threadIdx.x;

    if (t < KK) sa[t] = asum_ws[t];
    __syncthreads();

    #pragma unroll
    for (int i = 0; i < 16; ++i) {
        int idx = t + 1024 * i;
        sV[idx] = Vws[idx] - c[idx] * sa[idx >> 8];
    }
    __syncthreads();

    if (t < DD) {   // column (d) norms over k
        float s = 0.f;
        for (int k = 0; k < KK; ++k) { float v = sV[k * DD + t]; s += v * v; }
        colf[t] = 1.0f / fmaxf(sqrtf(s), 1e-12f);
    }
    __syncthreads();

    #pragma unroll
    for (int i = 0; i < 16; ++i) {
        int idx = t + 1024 * i;
        sV[idx] *= colf[idx & 255];
    }
    __syncthreads();

    {   // row (k) norms over d: 16 threads per row
        int k = t >> 4, p = t & 15;
        float s = 0.f;
        #pragma unroll
        for (int j = 0; j < 16; ++j) { float v = sV[k * DD + p + 16 * j]; s += v * v; }
        s += __shfl_xor(s, 1);
        s += __shfl_xor(s, 2);
        s += __shfl_xor(s, 4);
        s += __shfl_xor(s, 8);
        if (p == 0) rowf[k] = 1.0f / fmaxf(sqrtf(s), 1e-12f);
    }
    __syncthreads();

    #pragma unroll
    for (int i = 0; i < 16; ++i) {
        int idx = t + 1024 * i;
        y[idx] = sV[idx] * rowf[idx >> 8];
    }
}

extern "C" void kernel_launch(void* const* d_in, const int* in_sizes, int n_in,
                              void* d_out, int out_size, void* d_ws, size_t ws_size,
                              hipStream_t stream) {
    const float* x      = (const float*)d_in[0];
    const float* c      = (const float*)d_in[1];
    const float* conv_w = (const float*)d_in[2];
    const float* conv_b = (const float*)d_in[3];
    float* y   = (float*)d_out;
    float* Vws = (float*)d_ws;
    float* asum_ws = Vws + KK * DD;

    hipMemsetAsync(d_ws, 0, (KK * DD + KK) * sizeof(float), stream);
    netvlad_fused<<<GRID, BLOCK, 0, stream>>>(x, conv_w, conv_b, Vws, asum_ws);
    netvlad_finalize<<<1, 1024, 0, stream>>>(Vws, asum_ws, c, y);
}